// Round 1
// baseline (295.650 us; speedup 1.0000x reference)
//
#include <hip/hip_runtime.h>

// Problem constants (from reference setup_inputs)
#define BATCH 64
#define CH 3
#define HH 512
#define WW 512
#define HW (HH * WW)          // 262144
#define NSEG 256
#define EMB 768

// K1 tiling
#define BLOCKS_PER_BATCH 32
#define PIX_PER_BLOCK (HW / BLOCKS_PER_BATCH)   // 8192
#define THREADS 256
#define V4_ITERS (PIX_PER_BLOCK / 4 / THREADS)  // 8

// ws layout (floats/ints, 4B each):
//   sums:    [BATCH][NSEG][3] float   -> offset 0,            49152 elems
//   counts:  [BATCH][NSEG]    int     -> offset 49152,        16384 elems
//   partial: [4][BATCH][EMB]  float   -> offset 65536,        196608 elems
#define WS_SUMS_OFF    0
#define WS_CNT_OFF     (BATCH * NSEG * 3)
#define WS_PART_OFF    (WS_CNT_OFF + BATCH * NSEG)

// ---------------------------------------------------------------------------
// K1: per-(batch,segment) sums + counts via LDS histogram + global atomics
// ---------------------------------------------------------------------------
__global__ __launch_bounds__(THREADS) void seg_sum_kernel(
    const float* __restrict__ img, const int* __restrict__ seg,
    float* __restrict__ gsums, int* __restrict__ gcnt) {
  __shared__ float ls0[NSEG];
  __shared__ float ls1[NSEG];
  __shared__ float ls2[NSEG];
  __shared__ int   lc[NSEG];

  const int t = threadIdx.x;
  ls0[t] = 0.f; ls1[t] = 0.f; ls2[t] = 0.f; lc[t] = 0;
  __syncthreads();

  const int b   = blockIdx.x / BLOCKS_PER_BATCH;
  const int blk = blockIdx.x % BLOCKS_PER_BATCH;

  const size_t pixBase = (size_t)b * HW + (size_t)blk * PIX_PER_BLOCK;
  const int4*   seg4 = (const int4*)seg + (pixBase >> 2);
  const float4* r4   = (const float4*)img + (((size_t)(b * 3 + 0) * HW + (size_t)blk * PIX_PER_BLOCK) >> 2);
  const float4* g4   = (const float4*)img + (((size_t)(b * 3 + 1) * HW + (size_t)blk * PIX_PER_BLOCK) >> 2);
  const float4* b4   = (const float4*)img + (((size_t)(b * 3 + 2) * HW + (size_t)blk * PIX_PER_BLOCK) >> 2);

#pragma unroll
  for (int i = 0; i < V4_ITERS; ++i) {
    const int g = i * THREADS + t;
    const int4   s4 = seg4[g];
    const float4 rr = r4[g];
    const float4 gg = g4[g];
    const float4 bb = b4[g];

    atomicAdd(&ls0[s4.x], rr.x); atomicAdd(&ls1[s4.x], gg.x); atomicAdd(&ls2[s4.x], bb.x); atomicAdd(&lc[s4.x], 1);
    atomicAdd(&ls0[s4.y], rr.y); atomicAdd(&ls1[s4.y], gg.y); atomicAdd(&ls2[s4.y], bb.y); atomicAdd(&lc[s4.y], 1);
    atomicAdd(&ls0[s4.z], rr.z); atomicAdd(&ls1[s4.z], gg.z); atomicAdd(&ls2[s4.z], bb.z); atomicAdd(&lc[s4.z], 1);
    atomicAdd(&ls0[s4.w], rr.w); atomicAdd(&ls1[s4.w], gg.w); atomicAdd(&ls2[s4.w], bb.w); atomicAdd(&lc[s4.w], 1);
  }
  __syncthreads();

  // flush: one segment per thread
  const int s = t;
  atomicAdd(&gsums[((size_t)b * NSEG + s) * 3 + 0], ls0[s]);
  atomicAdd(&gsums[((size_t)b * NSEG + s) * 3 + 1], ls1[s]);
  atomicAdd(&gsums[((size_t)b * NSEG + s) * 3 + 2], ls2[s]);
  atomicAdd(&gcnt[(size_t)b * NSEG + s], lc[s]);
}

// ---------------------------------------------------------------------------
// K2: per (batch b, f-group g): partial[g][b][e] = sum_{f in group} p[f]*Wg[f][e]
//     where p = b_proj + mean_s(seg_means) @ W_proj
// ---------------------------------------------------------------------------
__global__ __launch_bounds__(THREADS) void proj_partial_kernel(
    const float* __restrict__ gsums, const int* __restrict__ gcnt,
    const float* __restrict__ Wp, const float* __restrict__ bp,
    const float* __restrict__ Wg, float* __restrict__ partial) {
  const int b   = blockIdx.x;   // 0..63
  const int grp = blockIdx.y;   // 0..3
  const int t   = threadIdx.x;  // 0..255

  __shared__ float r0[NSEG], r1[NSEG], r2[NSEG];
  const int cnt = gcnt[(size_t)b * NSEG + t];
  const float inv = 1.0f / (float)(cnt < 1 ? 1 : cnt);
  r0[t] = gsums[((size_t)b * NSEG + t) * 3 + 0] * inv;
  r1[t] = gsums[((size_t)b * NSEG + t) * 3 + 1] * inv;
  r2[t] = gsums[((size_t)b * NSEG + t) * 3 + 2] * inv;
  __syncthreads();
  for (int off = 128; off > 0; off >>= 1) {
    if (t < off) { r0[t] += r0[t + off]; r1[t] += r1[t + off]; r2[t] += r2[t + off]; }
    __syncthreads();
  }
  const float m0 = r0[0] * (1.0f / NSEG);
  const float m1 = r1[0] * (1.0f / NSEG);
  const float m2 = r2[0] * (1.0f / NSEG);

  __shared__ __align__(16) float pl[EMB];
  for (int e = t; e < EMB; e += THREADS)
    pl[e] = bp[e] + m0 * Wp[e] + m1 * Wp[EMB + e] + m2 * Wp[2 * EMB + e];
  __syncthreads();

  const int FPG = EMB / 4;  // 192 f-rows per group
  const int f0 = grp * FPG;
  float a0 = 0.f, a1 = 0.f, a2 = 0.f;
#pragma unroll 4
  for (int f = f0; f < f0 + FPG; ++f) {
    const float pf = pl[f];
    const float* row = Wg + (size_t)f * EMB;
    a0 += pf * row[t];
    a1 += pf * row[t + 256];
    a2 += pf * row[t + 512];
  }
  float* pt = partial + ((size_t)grp * BATCH + b) * EMB;
  pt[t]       = a0;
  pt[t + 256] = a1;
  pt[t + 512] = a2;
}

// ---------------------------------------------------------------------------
// K3: o[b] = b_gcn + sum_g partial[g][b]; broadcast to out[b][s][:] for all s
// ---------------------------------------------------------------------------
#define CHUNKS_PER_BATCH 16
#define V4_PER_CHUNK (NSEG * EMB / 4 / CHUNKS_PER_BATCH)  // 3072
#define V4_ITERS_K3 (V4_PER_CHUNK / THREADS)              // 12

__global__ __launch_bounds__(THREADS) void broadcast_kernel(
    const float* __restrict__ partial, const float* __restrict__ bg,
    float* __restrict__ out) {
  const int b     = blockIdx.x;  // 0..63
  const int chunk = blockIdx.y;  // 0..15
  const int t     = threadIdx.x;

  __shared__ __align__(16) float ol[EMB];
  for (int e = t; e < EMB; e += THREADS) {
    float v = bg[e];
    v += partial[((size_t)0 * BATCH + b) * EMB + e];
    v += partial[((size_t)1 * BATCH + b) * EMB + e];
    v += partial[((size_t)2 * BATCH + b) * EMB + e];
    v += partial[((size_t)3 * BATCH + b) * EMB + e];
    ol[e] = v;
  }
  __syncthreads();

  const float4* ol4 = (const float4*)ol;  // 192 float4 per row
  float4* out4 = (float4*)(out + (size_t)b * NSEG * EMB) + (size_t)chunk * V4_PER_CHUNK;
#pragma unroll
  for (int k = 0; k < V4_ITERS_K3; ++k) {
    const int v = k * THREADS + t;            // 0..3071
    const int w = (chunk * V4_PER_CHUNK + v) % (EMB / 4);
    out4[v] = ol4[w];
  }
}

// ---------------------------------------------------------------------------
extern "C" void kernel_launch(void* const* d_in, const int* in_sizes, int n_in,
                              void* d_out, int out_size, void* d_ws, size_t ws_size,
                              hipStream_t stream) {
  const float* img  = (const float*)d_in[0];
  const int*   seg  = (const int*)d_in[1];
  const float* Wp   = (const float*)d_in[2];
  const float* bp   = (const float*)d_in[3];
  const float* Wg   = (const float*)d_in[4];
  const float* bg   = (const float*)d_in[5];
  float* out = (float*)d_out;

  float* ws_f    = (float*)d_ws;
  float* gsums   = ws_f + WS_SUMS_OFF;
  int*   gcnt    = (int*)(ws_f + WS_CNT_OFF);
  float* partial = ws_f + WS_PART_OFF;

  // zero sums + counts
  hipMemsetAsync(d_ws, 0, (size_t)(BATCH * NSEG * 3 + BATCH * NSEG) * sizeof(float), stream);

  seg_sum_kernel<<<dim3(BATCH * BLOCKS_PER_BATCH), dim3(THREADS), 0, stream>>>(img, seg, gsums, gcnt);

  proj_partial_kernel<<<dim3(BATCH, 4), dim3(THREADS), 0, stream>>>(gsums, gcnt, Wp, bp, Wg, partial);

  broadcast_kernel<<<dim3(BATCH, CHUNKS_PER_BATCH), dim3(THREADS), 0, stream>>>(partial, bg, out);
}